// Round 5
// baseline (8373.876 us; speedup 1.0000x reference)
//
#include <hip/hip_runtime.h>
#include <hip/hip_bf16.h>

// ---------------------------------------------------------------------------
// AJ-RNN forward (B=128,T=256,D=64,H=512), persistent kernel, round 5.
// Same decomposition as round 4 (64 blocks, block j owns h-cols [8j,8j+8) of
// both layers, weights+cell state in LDS). NEW: fence-free device coherence —
// cross-block data (cur/h1/h2) moves via relaxed agent-scope (sc1) atomics
// that bypass the non-coherent per-XCD L2s; barriers are relaxed atomic
// counters with an explicit vmcnt drain. No buffer_inv/wbl2 anywhere.
// ---------------------------------------------------------------------------

typedef __bf16  v8bf  __attribute__((ext_vector_type(8)));
typedef float   f32x4 __attribute__((ext_vector_type(4)));

constexpr int B_ = 128, T_ = 256, D_ = 64, H_ = 512;

// workspace layout (bytes)
constexpr size_t OFF_WP1 = 0;        // gate-interleaved packed [k0;r0]: 2359296
constexpr size_t OFF_WP2 = 2359296;  // gate-interleaved packed [k1;r1]: 4194304
constexpr size_t OFF_WPP = 6553600;  // plain packed W:                    65536
constexpr size_t OFF_H1A = 6619136;  // h1 ping bf16 131072
constexpr size_t OFF_H1B = 6750208;  // h1 pong
constexpr size_t OFF_H2A = 6881280;  // h2 ping
constexpr size_t OFF_H2B = 7012352;  // h2 pong
constexpr size_t OFF_CUR = 7143424;  // cur bf16 [128][64] = 16384
constexpr size_t OFF_CTR = 7159808;  // barrier counter (256 B slot)

__device__ __forceinline__ v8bf ldv(const __hip_bfloat16* p) {
  return *reinterpret_cast<const v8bf*>(p);
}
// agent-coherent 16B fragment load (2x dwordx2 sc1, bypasses XCD L2)
__device__ __forceinline__ v8bf ldc(const __hip_bfloat16* p) {
  unsigned long long lo = __hip_atomic_load((const unsigned long long*)p,
                                            __ATOMIC_RELAXED, __HIP_MEMORY_SCOPE_AGENT);
  unsigned long long hi = __hip_atomic_load((const unsigned long long*)(p + 4),
                                            __ATOMIC_RELAXED, __HIP_MEMORY_SCOPE_AGENT);
  union { unsigned long long q[2]; v8bf v; } u;
  u.q[0] = lo; u.q[1] = hi;
  return u.v;
}
// agent-coherent store of two adjacent bf16 (4B aligned)
__device__ __forceinline__ void stc2(__hip_bfloat16* p, float a, float b) {
  union { unsigned u; __hip_bfloat16 h[2]; } v;
  v.h[0] = __float2bfloat16(a); v.h[1] = __float2bfloat16(b);
  __hip_atomic_store((unsigned*)p, v.u, __ATOMIC_RELAXED, __HIP_MEMORY_SCOPE_AGENT);
}
__device__ __forceinline__ float sigf(float x) { return 1.0f / (1.0f + __expf(-x)); }
__device__ __forceinline__ float tanhfast(float x) {
  x = fminf(15.0f, fmaxf(-15.0f, x));
  float e = __expf(-2.0f * x);
  return (1.0f - e) / (1.0f + e);
}

// fence-free device barrier: sc1 stores are already at the coherent level once
// vmcnt retires, so arrival needs only a vmcnt drain + relaxed RMW; observers
// poll with relaxed loads (no L2 invalidate per poll, unlike acquire).
__device__ __forceinline__ void gbar(unsigned* ctr, unsigned target) {
  __syncthreads();   // compiler emits s_waitcnt vmcnt(0) before s_barrier
  if (threadIdx.x == 0) {
    asm volatile("s_waitcnt vmcnt(0)" ::: "memory");
    __hip_atomic_fetch_add(ctr, 1u, __ATOMIC_RELAXED, __HIP_MEMORY_SCOPE_AGENT);
    while (__hip_atomic_load(ctr, __ATOMIC_RELAXED, __HIP_MEMORY_SCOPE_AGENT) < target)
      __builtin_amdgcn_s_sleep(2);
  }
  __syncthreads();
}

// ---------------------------------------------------------------------------
// Gate-interleaved fragment packer (float32 in, bf16 frags out), as round 4:
// tile (2j+0) = [i|f], tile (2j+1) = [g|o] for h-cols [8j,8j+8).
// ---------------------------------------------------------------------------
__global__ __launch_bounds__(256) void pack_gi(
    const float* __restrict__ kp, const float* __restrict__ rp,
    int krows, int nkc, __hip_bfloat16* __restrict__ out) {
  int tid = blockIdx.x * 256 + threadIdx.x;
  int total = 128 * nkc * 64;
  if (tid >= total) return;
  int L  = tid & 63;
  int kc = (tid >> 6) % nkc;
  int ct = tid / (64 * nkc);
  int c16  = L & 15;
  int gate = (ct & 1) * 2 + (c16 >> 3);
  int hcol = 8 * (ct >> 1) + (c16 & 7);
  int n  = gate * 512 + hcol;
  int kb = kc * 32 + (L >> 4) * 8;
  __hip_bfloat16* dst = out + (size_t)tid * 8;
#pragma unroll
  for (int e = 0; e < 8; ++e) {
    int kk = kb + e;
    float v = (kk < krows) ? kp[kk * 2048 + n] : rp[(kk - krows) * 2048 + n];
    dst[e] = __float2bfloat16(v);
  }
}

// plain packer for the imputation weight W (512x64), nct=4, nkc=16
__global__ __launch_bounds__(256) void pack_plain(
    const float* __restrict__ kp, __hip_bfloat16* __restrict__ out) {
  int tid = blockIdx.x * 256 + threadIdx.x;
  if (tid >= 4 * 16 * 64) return;
  int L  = tid & 63;
  int kc = (tid >> 6) % 16;
  int ct = tid / (64 * 16);
  int n  = ct * 16 + (L & 15);
  int kb = kc * 32 + (L >> 4) * 8;
  __hip_bfloat16* dst = out + (size_t)tid * 8;
#pragma unroll
  for (int e = 0; e < 8; ++e) dst[e] = __float2bfloat16(kp[(kb + e) * 64 + n]);
}

__global__ __launch_bounds__(256) void init_misc(
    __hip_bfloat16* __restrict__ h1a, __hip_bfloat16* __restrict__ h2a,
    unsigned* __restrict__ ctr) {
  int idx = blockIdx.x * 256 + threadIdx.x;   // 65536
  h1a[idx] = __float2bfloat16(0.0f);
  h2a[idx] = __float2bfloat16(0.0f);
  if (idx == 0) *ctr = 0u;
  // kernel-end implicit system release flushes these to the coherent level.
}

// ---------------------------------------------------------------------------
__global__ __launch_bounds__(256) void rnn_persist(
    const float* __restrict__ x,
    const __hip_bfloat16* __restrict__ W1g,
    const __hip_bfloat16* __restrict__ W2g,
    const __hip_bfloat16* __restrict__ WpPg,
    const float* __restrict__ b0,
    const float* __restrict__ b1,
    const float* __restrict__ biasD,
    __hip_bfloat16* __restrict__ curg,
    __hip_bfloat16* __restrict__ h1a, __hip_bfloat16* __restrict__ h1b,
    __hip_bfloat16* __restrict__ h2a, __hip_bfloat16* __restrict__ h2b,
    unsigned* ctr,
    float* __restrict__ outp, float* __restrict__ lastp) {
  __shared__ __hip_bfloat16 lW1[2][18][64 * 8];   // 36864 B
  __shared__ __hip_bfloat16 lW2[2][32][64 * 8];   // 65536 B
  __shared__ float zb[4][2][2][16][16];           // 16384 B
  __shared__ float predpart[4][16][16];           //  4096 B
  __shared__ float lc1[1024];                     //  4096 B
  __shared__ float lc2[1024];                     //  4096 B
  __shared__ float lb0[4][8], lb1[4][8];          //   256 B

  const int j   = blockIdx.x;        // owns h-cols [8j, 8j+8)
  const int tid = threadIdx.x;
  const int w = tid >> 6, L = tid & 63, m = L & 15, q = L >> 4;

  // ---- one-time: weight slices -> LDS, biases, zero cell state ----
  {
    const __hip_bfloat16* s1 = W1g + (size_t)(2 * j) * 18 * 512;
    __hip_bfloat16* d1 = &lW1[0][0][0];
    for (int i = tid * 8; i < 2 * 18 * 512; i += 256 * 8)
      *reinterpret_cast<v8bf*>(d1 + i) = ldv(s1 + i);
    const __hip_bfloat16* s2 = W2g + (size_t)(2 * j) * 32 * 512;
    __hip_bfloat16* d2 = &lW2[0][0][0];
    for (int i = tid * 8; i < 2 * 32 * 512; i += 256 * 8)
      *reinterpret_cast<v8bf*>(d2 + i) = ldv(s2 + i);
  }
  if (tid < 32) {
    int g = tid >> 3, c = tid & 7;
    lb0[g][c] = b0[g * 512 + 8 * j + c];
    lb1[g][c] = b1[g * 512 + 8 * j + c];
  }
  for (int i = tid; i < 1024; i += 256) { lc1[i] = 0.f; lc2[i] = 0.f; }
  __syncthreads();

  const int pmt = j >> 2, pnt = j & 3;     // pred job (blocks 0..31)
  const int R0 = pmt * 16, C0 = pnt * 16;
  unsigned ph = 0;

  for (int t = 0; t < T_; ++t) {
    const __hip_bfloat16* h1r = (t & 1) ? h1b : h1a;
    __hip_bfloat16*       h1w = (t & 1) ? h1a : h1b;
    const __hip_bfloat16* h2r = (t & 1) ? h2b : h2a;
    __hip_bfloat16*       h2w = (t & 1) ? h2a : h2b;

    // ---------------- Phase P: pred tile + cur (blocks 0..31) -------------
    if (j < 32) {
      if (t > 0) {
        f32x4 acc = {0.f, 0.f, 0.f, 0.f};
#pragma unroll
        for (int kk = 0; kk < 4; ++kk) {
          int kc = w * 4 + kk;
          v8bf a  = ldc(h2r + (size_t)(R0 + m) * H_ + kc * 32 + q * 8);
          v8bf bb = ldv(WpPg + ((size_t)(pnt * 16 + kc) * 64 + L) * 8);
          acc = __builtin_amdgcn_mfma_f32_16x16x32_bf16(a, bb, acc, 0, 0, 0);
        }
#pragma unroll
        for (int r = 0; r < 4; ++r) predpart[w][q * 4 + r][m] = acc[r];
      }
      __syncthreads();
      if (tid < 128) {
        int row = tid >> 3, c0 = (tid & 7) * 2;
        int R = R0 + row;
        float xv0 = x[((size_t)R * T_ + t) * D_ + C0 + c0];
        float xv1 = x[((size_t)R * T_ + t) * D_ + C0 + c0 + 1];
        float cv0 = xv0, cv1 = xv1;
        if (t > 0) {
          float pv0 = predpart[0][row][c0]     + predpart[1][row][c0] +
                      predpart[2][row][c0]     + predpart[3][row][c0] +
                      biasD[C0 + c0];
          float pv1 = predpart[0][row][c0 + 1] + predpart[1][row][c0 + 1] +
                      predpart[2][row][c0 + 1] + predpart[3][row][c0 + 1] +
                      biasD[C0 + c0 + 1];
          size_t orow = ((size_t)R * (T_ - 1) + (t - 1)) * D_ + C0 + c0;
          outp[orow]     = pv0;
          outp[orow + 1] = pv1;
          if (xv0 == 128.0f) cv0 = pv0;
          if (xv1 == 128.0f) cv1 = pv1;
        }
        stc2(curg + R * D_ + C0 + c0, cv0, cv1);
      }
    }
    gbar(ctr, 64u * (++ph));

    // ---------------- Phase L1: z1 = [cur | h1_{t-1}] @ W1 ----------------
    {
      f32x4 acc[2][2] = {{{0.f,0.f,0.f,0.f},{0.f,0.f,0.f,0.f}},
                         {{0.f,0.f,0.f,0.f},{0.f,0.f,0.f,0.f}}};
      const int mt0 = 2 * w;
#pragma unroll
      for (int kc = 0; kc < 18; ++kc) {
        v8bf bf0 = ldv(&lW1[0][kc][L * 8]);
        v8bf bf1 = ldv(&lW1[1][kc][L * 8]);
#pragma unroll
        for (int u = 0; u < 2; ++u) {
          int gr = (mt0 + u) * 16 + m;
          v8bf a = (kc < 2) ? ldc(curg + gr * D_ + kc * 32 + q * 8)
                            : ldc(h1r + (size_t)gr * H_ + (kc - 2) * 32 + q * 8);
          acc[u][0] = __builtin_amdgcn_mfma_f32_16x16x32_bf16(a, bf0, acc[u][0], 0, 0, 0);
          acc[u][1] = __builtin_amdgcn_mfma_f32_16x16x32_bf16(a, bf1, acc[u][1], 0, 0, 0);
        }
      }
#pragma unroll
      for (int u = 0; u < 2; ++u)
#pragma unroll
        for (int s = 0; s < 2; ++s)
#pragma unroll
          for (int r = 0; r < 4; ++r) zb[w][u][s][q * 4 + r][m] = acc[u][s][r];
    }
    __syncthreads();
    {
#pragma unroll
      for (int it = 0; it < 2; ++it) {
        int pid = tid + 256 * it;          // 0..511: gr (128) x col-pair (4)
        int gr = pid >> 2, c0 = (pid & 3) * 2;
        int mt = gr >> 4, rl = gr & 15, wv = mt >> 1, u = mt & 1;
        float hn[2];
#pragma unroll
        for (int d = 0; d < 2; ++d) {
          int c = c0 + d;
          float iv = zb[wv][u][0][rl][c]     + lb0[0][c];
          float fv = zb[wv][u][0][rl][c + 8] + lb0[1][c];
          float gv = zb[wv][u][1][rl][c]     + lb0[2][c];
          float ov = zb[wv][u][1][rl][c + 8] + lb0[3][c];
          float ig = sigf(iv), fg = sigf(fv), gg = tanhfast(gv), og = sigf(ov);
          float cn = fg * lc1[gr * 8 + c] + ig * gg;
          hn[d] = og * tanhfast(cn);
          lc1[gr * 8 + c] = cn;
        }
        stc2(h1w + (size_t)gr * H_ + 8 * j + c0, hn[0], hn[1]);
      }
    }
    gbar(ctr, 64u * (++ph));

    // ---------------- Phase L2: z2 = [h1_t | h2_{t-1}] @ W2 ---------------
    {
      f32x4 acc[2][2] = {{{0.f,0.f,0.f,0.f},{0.f,0.f,0.f,0.f}},
                         {{0.f,0.f,0.f,0.f},{0.f,0.f,0.f,0.f}}};
      const int mt0 = 2 * w;
#pragma unroll
      for (int kc = 0; kc < 32; ++kc) {
        v8bf bf0 = ldv(&lW2[0][kc][L * 8]);
        v8bf bf1 = ldv(&lW2[1][kc][L * 8]);
#pragma unroll
        for (int u = 0; u < 2; ++u) {
          int gr = (mt0 + u) * 16 + m;
          v8bf a = (kc < 16) ? ldc(h1w + (size_t)gr * H_ + kc * 32 + q * 8)
                             : ldc(h2r + (size_t)gr * H_ + (kc - 16) * 32 + q * 8);
          acc[u][0] = __builtin_amdgcn_mfma_f32_16x16x32_bf16(a, bf0, acc[u][0], 0, 0, 0);
          acc[u][1] = __builtin_amdgcn_mfma_f32_16x16x32_bf16(a, bf1, acc[u][1], 0, 0, 0);
        }
      }
#pragma unroll
      for (int u = 0; u < 2; ++u)
#pragma unroll
        for (int s = 0; s < 2; ++s)
#pragma unroll
          for (int r = 0; r < 4; ++r) zb[w][u][s][q * 4 + r][m] = acc[u][s][r];
    }
    __syncthreads();
    {
#pragma unroll
      for (int it = 0; it < 2; ++it) {
        int pid = tid + 256 * it;
        int gr = pid >> 2, c0 = (pid & 3) * 2;
        int mt = gr >> 4, rl = gr & 15, wv = mt >> 1, u = mt & 1;
        float hn[2];
#pragma unroll
        for (int d = 0; d < 2; ++d) {
          int c = c0 + d;
          float iv = zb[wv][u][0][rl][c]     + lb1[0][c];
          float fv = zb[wv][u][0][rl][c + 8] + lb1[1][c];
          float gv = zb[wv][u][1][rl][c]     + lb1[2][c];
          float ov = zb[wv][u][1][rl][c + 8] + lb1[3][c];
          float ig = sigf(iv), fg = sigf(fv), gg = tanhfast(gv), og = sigf(ov);
          float cn = fg * lc2[gr * 8 + c] + ig * gg;
          hn[d] = og * tanhfast(cn);
          lc2[gr * 8 + c] = cn;
        }
        stc2(h2w + (size_t)gr * H_ + 8 * j + c0, hn[0], hn[1]);
        if (t == T_ - 1) {
          lastp[(size_t)gr * H_ + 8 * j + c0]     = hn[0];
          lastp[(size_t)gr * H_ + 8 * j + c0 + 1] = hn[1];
        }
      }
    }
    gbar(ctr, 64u * (++ph));
  }
}

// ---------------------------------------------------------------------------
extern "C" void kernel_launch(void* const* d_in, const int* in_sizes, int n_in,
                              void* d_out, int out_size, void* d_ws, size_t ws_size,
                              hipStream_t stream) {
  const float* x    = (const float*)d_in[0];
  const float* k0   = (const float*)d_in[1];
  const float* r0   = (const float*)d_in[2];
  const float* b0   = (const float*)d_in[3];
  const float* k1   = (const float*)d_in[4];
  const float* r1   = (const float*)d_in[5];
  const float* b1   = (const float*)d_in[6];
  const float* W    = (const float*)d_in[7];
  const float* bias = (const float*)d_in[8];

  char* ws = (char*)d_ws;
  __hip_bfloat16* Wp1 = (__hip_bfloat16*)(ws + OFF_WP1);
  __hip_bfloat16* Wp2 = (__hip_bfloat16*)(ws + OFF_WP2);
  __hip_bfloat16* WpP = (__hip_bfloat16*)(ws + OFF_WPP);
  __hip_bfloat16* h1a = (__hip_bfloat16*)(ws + OFF_H1A);
  __hip_bfloat16* h1b = (__hip_bfloat16*)(ws + OFF_H1B);
  __hip_bfloat16* h2a = (__hip_bfloat16*)(ws + OFF_H2A);
  __hip_bfloat16* h2b = (__hip_bfloat16*)(ws + OFF_H2B);
  __hip_bfloat16* cur = (__hip_bfloat16*)(ws + OFF_CUR);
  unsigned*       ctr = (unsigned*)(ws + OFF_CTR);

  pack_gi<<<576, 256, 0, stream>>>(k0, r0, 64, 18, Wp1);
  pack_gi<<<1024, 256, 0, stream>>>(k1, r1, 512, 32, Wp2);
  pack_plain<<<16, 256, 0, stream>>>(W, WpP);
  init_misc<<<256, 256, 0, stream>>>(h1a, h2a, ctr);

  float* outp = (float*)d_out;
  float* last = outp + (size_t)B_ * (T_ - 1) * D_;

  rnn_persist<<<64, 256, 0, stream>>>(x, Wp1, Wp2, WpP, b0, b1, bias,
                                      cur, h1a, h1b, h2a, h2b, ctr, outp, last);
}

// Round 6
// 7688.399 us; speedup vs baseline: 1.0892x; 1.0892x over previous
//
#include <hip/hip_runtime.h>
#include <hip/hip_bf16.h>

// ---------------------------------------------------------------------------
// AJ-RNN forward (B=128,T=256,D=64,H=512), persistent kernel, round 6.
// Same decomposition + sc1 data path as round 5 (proven correct). NEW barrier:
// per-block arrival slots (relaxed stores, distinct addresses) + master-block
// ballot poll + replicated go-flag broadcast (16 lines, <=4 pollers each).
// Removes the single-line RMW/poll congestion that cost ~10.7 us/barrier.
// ---------------------------------------------------------------------------

typedef __bf16  v8bf  __attribute__((ext_vector_type(8)));
typedef float   f32x4 __attribute__((ext_vector_type(4)));

constexpr int B_ = 128, T_ = 256, D_ = 64, H_ = 512;

// workspace layout (bytes)
constexpr size_t OFF_WP1 = 0;        // gate-interleaved packed [k0;r0]: 2359296
constexpr size_t OFF_WP2 = 2359296;  // gate-interleaved packed [k1;r1]: 4194304
constexpr size_t OFF_WPP = 6553600;  // plain packed W:                    65536
constexpr size_t OFF_H1A = 6619136;  // h1 ping bf16 131072
constexpr size_t OFF_H1B = 6750208;  // h1 pong
constexpr size_t OFF_H2A = 6881280;  // h2 ping
constexpr size_t OFF_H2B = 7012352;  // h2 pong
constexpr size_t OFF_CUR = 7143424;  // cur bf16 [128][64] = 16384
constexpr size_t OFF_BAR = 7159808;  // barrier region: arr[64] + go lines (4 KB)

__device__ __forceinline__ v8bf ldv(const __hip_bfloat16* p) {
  return *reinterpret_cast<const v8bf*>(p);
}
// agent-coherent 16B fragment load (2x dwordx2 sc1, bypasses XCD L2)
__device__ __forceinline__ v8bf ldc(const __hip_bfloat16* p) {
  unsigned long long lo = __hip_atomic_load((const unsigned long long*)p,
                                            __ATOMIC_RELAXED, __HIP_MEMORY_SCOPE_AGENT);
  unsigned long long hi = __hip_atomic_load((const unsigned long long*)(p + 4),
                                            __ATOMIC_RELAXED, __HIP_MEMORY_SCOPE_AGENT);
  union { unsigned long long q[2]; v8bf v; } u;
  u.q[0] = lo; u.q[1] = hi;
  return u.v;
}
// agent-coherent store of two adjacent bf16 (4B aligned)
__device__ __forceinline__ void stc2(__hip_bfloat16* p, float a, float b) {
  union { unsigned u; __hip_bfloat16 h[2]; } v;
  v.h[0] = __float2bfloat16(a); v.h[1] = __float2bfloat16(b);
  __hip_atomic_store((unsigned*)p, v.u, __ATOMIC_RELAXED, __HIP_MEMORY_SCOPE_AGENT);
}
__device__ __forceinline__ float sigf(float x) { return 1.0f / (1.0f + __expf(-x)); }
__device__ __forceinline__ float tanhfast(float x) {
  x = fminf(15.0f, fmaxf(-15.0f, x));
  float e = __expf(-2.0f * x);
  return (1.0f - e) / (1.0f + e);
}

// Decontended device barrier.
//  arr[j]: per-block arrival slot (block j stores phase number; distinct addrs)
//  go[k*32]: 16 replicated release lines (128 B apart); worker j polls j&15.
//  Block 63 is the master: ballots arr with one wave-wide load, broadcasts go.
//  Producers = blocks [0, nprod); nprod=32 for phase P, 63 for L1/L2
//  (master's own arrival is implicit: it polls only after its compute+sync).
// __syncthreads() entry drains each wave's stores (compiler emits vmcnt(0)
// before s_barrier), so arrival implies this block's sc1 data is at the LLC.
__device__ __forceinline__ void gbar(unsigned* arr, unsigned* go, int j,
                                     unsigned ph, int nprod) {
  __syncthreads();
  if (j == 63) {
    if (threadIdx.x < 64) {
      const unsigned long long need =
          (nprod >= 64) ? ~0ull : ((1ull << nprod) - 1ull);
      for (;;) {
        unsigned v = __hip_atomic_load(arr + threadIdx.x, __ATOMIC_RELAXED,
                                       __HIP_MEMORY_SCOPE_AGENT);
        if ((__ballot(v >= ph) & need) == need) break;
        __builtin_amdgcn_s_sleep(2);
      }
    }
    __syncthreads();
    if (threadIdx.x < 16)
      __hip_atomic_store(go + threadIdx.x * 32, ph, __ATOMIC_RELAXED,
                         __HIP_MEMORY_SCOPE_AGENT);
  } else {
    if (threadIdx.x == 0) {
      if (j < nprod)
        __hip_atomic_store(arr + j, ph, __ATOMIC_RELAXED,
                           __HIP_MEMORY_SCOPE_AGENT);
      while (__hip_atomic_load(go + (j & 15) * 32, __ATOMIC_RELAXED,
                               __HIP_MEMORY_SCOPE_AGENT) < ph)
        __builtin_amdgcn_s_sleep(4);
    }
    __syncthreads();
  }
}

// ---------------------------------------------------------------------------
// Gate-interleaved fragment packer (float32 in, bf16 frags out):
// tile (2j+0) = [i|f], tile (2j+1) = [g|o] for h-cols [8j,8j+8).
// ---------------------------------------------------------------------------
__global__ __launch_bounds__(256) void pack_gi(
    const float* __restrict__ kp, const float* __restrict__ rp,
    int krows, int nkc, __hip_bfloat16* __restrict__ out) {
  int tid = blockIdx.x * 256 + threadIdx.x;
  int total = 128 * nkc * 64;
  if (tid >= total) return;
  int L  = tid & 63;
  int kc = (tid >> 6) % nkc;
  int ct = tid / (64 * nkc);
  int c16  = L & 15;
  int gate = (ct & 1) * 2 + (c16 >> 3);
  int hcol = 8 * (ct >> 1) + (c16 & 7);
  int n  = gate * 512 + hcol;
  int kb = kc * 32 + (L >> 4) * 8;
  __hip_bfloat16* dst = out + (size_t)tid * 8;
#pragma unroll
  for (int e = 0; e < 8; ++e) {
    int kk = kb + e;
    float v = (kk < krows) ? kp[kk * 2048 + n] : rp[(kk - krows) * 2048 + n];
    dst[e] = __float2bfloat16(v);
  }
}

// plain packer for the imputation weight W (512x64), nct=4, nkc=16
__global__ __launch_bounds__(256) void pack_plain(
    const float* __restrict__ kp, __hip_bfloat16* __restrict__ out) {
  int tid = blockIdx.x * 256 + threadIdx.x;
  if (tid >= 4 * 16 * 64) return;
  int L  = tid & 63;
  int kc = (tid >> 6) % 16;
  int ct = tid / (64 * 16);
  int n  = ct * 16 + (L & 15);
  int kb = kc * 32 + (L >> 4) * 8;
  __hip_bfloat16* dst = out + (size_t)tid * 8;
#pragma unroll
  for (int e = 0; e < 8; ++e) dst[e] = __float2bfloat16(kp[(kb + e) * 64 + n]);
}

__global__ __launch_bounds__(256) void init_misc(
    __hip_bfloat16* __restrict__ h1a, __hip_bfloat16* __restrict__ h2a,
    unsigned* __restrict__ bar) {
  int idx = blockIdx.x * 256 + threadIdx.x;   // 65536
  h1a[idx] = __float2bfloat16(0.0f);
  h2a[idx] = __float2bfloat16(0.0f);
  if (idx < 1024) bar[idx] = 0u;   // arr[64] + go lines, all zeroed
  // kernel-end implicit system release flushes these to the coherent level.
}

// ---------------------------------------------------------------------------
__global__ __launch_bounds__(256) void rnn_persist(
    const float* __restrict__ x,
    const __hip_bfloat16* __restrict__ W1g,
    const __hip_bfloat16* __restrict__ W2g,
    const __hip_bfloat16* __restrict__ WpPg,
    const float* __restrict__ b0,
    const float* __restrict__ b1,
    const float* __restrict__ biasD,
    __hip_bfloat16* __restrict__ curg,
    __hip_bfloat16* __restrict__ h1a, __hip_bfloat16* __restrict__ h1b,
    __hip_bfloat16* __restrict__ h2a, __hip_bfloat16* __restrict__ h2b,
    unsigned* barp,
    float* __restrict__ outp, float* __restrict__ lastp) {
  __shared__ __hip_bfloat16 lW1[2][18][64 * 8];   // 36864 B
  __shared__ __hip_bfloat16 lW2[2][32][64 * 8];   // 65536 B
  __shared__ float zb[4][2][2][16][16];           // 16384 B
  __shared__ float predpart[4][16][16];           //  4096 B
  __shared__ float lc1[1024];                     //  4096 B
  __shared__ float lc2[1024];                     //  4096 B
  __shared__ float lb0[4][8], lb1[4][8];          //   256 B

  unsigned* arr = barp;         // 64 x u32 arrival slots
  unsigned* go  = barp + 64;    // 16 release lines, stride 32 u32 (128 B)

  const int j   = blockIdx.x;        // owns h-cols [8j, 8j+8)
  const int tid = threadIdx.x;
  const int w = tid >> 6, L = tid & 63, m = L & 15, q = L >> 4;

  // ---- one-time: weight slices -> LDS, biases, zero cell state ----
  {
    const __hip_bfloat16* s1 = W1g + (size_t)(2 * j) * 18 * 512;
    __hip_bfloat16* d1 = &lW1[0][0][0];
    for (int i = tid * 8; i < 2 * 18 * 512; i += 256 * 8)
      *reinterpret_cast<v8bf*>(d1 + i) = ldv(s1 + i);
    const __hip_bfloat16* s2 = W2g + (size_t)(2 * j) * 32 * 512;
    __hip_bfloat16* d2 = &lW2[0][0][0];
    for (int i = tid * 8; i < 2 * 32 * 512; i += 256 * 8)
      *reinterpret_cast<v8bf*>(d2 + i) = ldv(s2 + i);
  }
  if (tid < 32) {
    int g = tid >> 3, c = tid & 7;
    lb0[g][c] = b0[g * 512 + 8 * j + c];
    lb1[g][c] = b1[g * 512 + 8 * j + c];
  }
  for (int i = tid; i < 1024; i += 256) { lc1[i] = 0.f; lc2[i] = 0.f; }
  __syncthreads();

  const int pmt = j >> 2, pnt = j & 3;     // pred job (blocks 0..31)
  const int R0 = pmt * 16, C0 = pnt * 16;
  unsigned ph = 0;

  for (int t = 0; t < T_; ++t) {
    const __hip_bfloat16* h1r = (t & 1) ? h1b : h1a;
    __hip_bfloat16*       h1w = (t & 1) ? h1a : h1b;
    const __hip_bfloat16* h2r = (t & 1) ? h2b : h2a;
    __hip_bfloat16*       h2w = (t & 1) ? h2a : h2b;

    // ---------------- Phase P: pred tile + cur (blocks 0..31) -------------
    if (j < 32) {
      if (t > 0) {
        f32x4 acc = {0.f, 0.f, 0.f, 0.f};
#pragma unroll
        for (int kk = 0; kk < 4; ++kk) {
          int kc = w * 4 + kk;
          v8bf a  = ldc(h2r + (size_t)(R0 + m) * H_ + kc * 32 + q * 8);
          v8bf bb = ldv(WpPg + ((size_t)(pnt * 16 + kc) * 64 + L) * 8);
          acc = __builtin_amdgcn_mfma_f32_16x16x32_bf16(a, bb, acc, 0, 0, 0);
        }
#pragma unroll
        for (int r = 0; r < 4; ++r) predpart[w][q * 4 + r][m] = acc[r];
      }
      __syncthreads();
      if (tid < 128) {
        int row = tid >> 3, c0 = (tid & 7) * 2;
        int R = R0 + row;
        float xv0 = x[((size_t)R * T_ + t) * D_ + C0 + c0];
        float xv1 = x[((size_t)R * T_ + t) * D_ + C0 + c0 + 1];
        float cv0 = xv0, cv1 = xv1;
        if (t > 0) {
          float pv0 = predpart[0][row][c0]     + predpart[1][row][c0] +
                      predpart[2][row][c0]     + predpart[3][row][c0] +
                      biasD[C0 + c0];
          float pv1 = predpart[0][row][c0 + 1] + predpart[1][row][c0 + 1] +
                      predpart[2][row][c0 + 1] + predpart[3][row][c0 + 1] +
                      biasD[C0 + c0 + 1];
          size_t orow = ((size_t)R * (T_ - 1) + (t - 1)) * D_ + C0 + c0;
          outp[orow]     = pv0;
          outp[orow + 1] = pv1;
          if (xv0 == 128.0f) cv0 = pv0;
          if (xv1 == 128.0f) cv1 = pv1;
        }
        stc2(curg + R * D_ + C0 + c0, cv0, cv1);
      }
    }
    gbar(arr, go, j, ++ph, 32);

    // ---------------- Phase L1: z1 = [cur | h1_{t-1}] @ W1 ----------------
    {
      f32x4 acc[2][2] = {{{0.f,0.f,0.f,0.f},{0.f,0.f,0.f,0.f}},
                         {{0.f,0.f,0.f,0.f},{0.f,0.f,0.f,0.f}}};
      const int mt0 = 2 * w;
#pragma unroll
      for (int kc = 0; kc < 18; ++kc) {
        v8bf bf0 = ldv(&lW1[0][kc][L * 8]);
        v8bf bf1 = ldv(&lW1[1][kc][L * 8]);
#pragma unroll
        for (int u = 0; u < 2; ++u) {
          int gr = (mt0 + u) * 16 + m;
          v8bf a = (kc < 2) ? ldc(curg + gr * D_ + kc * 32 + q * 8)
                            : ldc(h1r + (size_t)gr * H_ + (kc - 2) * 32 + q * 8);
          acc[u][0] = __builtin_amdgcn_mfma_f32_16x16x32_bf16(a, bf0, acc[u][0], 0, 0, 0);
          acc[u][1] = __builtin_amdgcn_mfma_f32_16x16x32_bf16(a, bf1, acc[u][1], 0, 0, 0);
        }
      }
#pragma unroll
      for (int u = 0; u < 2; ++u)
#pragma unroll
        for (int s = 0; s < 2; ++s)
#pragma unroll
          for (int r = 0; r < 4; ++r) zb[w][u][s][q * 4 + r][m] = acc[u][s][r];
    }
    __syncthreads();
    {
#pragma unroll
      for (int it = 0; it < 2; ++it) {
        int pid = tid + 256 * it;          // 0..511: gr (128) x col-pair (4)
        int gr = pid >> 2, c0 = (pid & 3) * 2;
        int mt = gr >> 4, rl = gr & 15, wv = mt >> 1, u = mt & 1;
        float hn[2];
#pragma unroll
        for (int d = 0; d < 2; ++d) {
          int c = c0 + d;
          float iv = zb[wv][u][0][rl][c]     + lb0[0][c];
          float fv = zb[wv][u][0][rl][c + 8] + lb0[1][c];
          float gv = zb[wv][u][1][rl][c]     + lb0[2][c];
          float ov = zb[wv][u][1][rl][c + 8] + lb0[3][c];
          float ig = sigf(iv), fg = sigf(fv), gg = tanhfast(gv), og = sigf(ov);
          float cn = fg * lc1[gr * 8 + c] + ig * gg;
          hn[d] = og * tanhfast(cn);
          lc1[gr * 8 + c] = cn;
        }
        stc2(h1w + (size_t)gr * H_ + 8 * j + c0, hn[0], hn[1]);
      }
    }
    gbar(arr, go, j, ++ph, 63);

    // ---------------- Phase L2: z2 = [h1_t | h2_{t-1}] @ W2 ---------------
    {
      f32x4 acc[2][2] = {{{0.f,0.f,0.f,0.f},{0.f,0.f,0.f,0.f}},
                         {{0.f,0.f,0.f,0.f},{0.f,0.f,0.f,0.f}}};
      const int mt0 = 2 * w;
#pragma unroll
      for (int kc = 0; kc < 32; ++kc) {
        v8bf bf0 = ldv(&lW2[0][kc][L * 8]);
        v8bf bf1 = ldv(&lW2[1][kc][L * 8]);
#pragma unroll
        for (int u = 0; u < 2; ++u) {
          int gr = (mt0 + u) * 16 + m;
          v8bf a = (kc < 16) ? ldc(h1w + (size_t)gr * H_ + kc * 32 + q * 8)
                             : ldc(h2r + (size_t)gr * H_ + (kc - 16) * 32 + q * 8);
          acc[u][0] = __builtin_amdgcn_mfma_f32_16x16x32_bf16(a, bf0, acc[u][0], 0, 0, 0);
          acc[u][1] = __builtin_amdgcn_mfma_f32_16x16x32_bf16(a, bf1, acc[u][1], 0, 0, 0);
        }
      }
#pragma unroll
      for (int u = 0; u < 2; ++u)
#pragma unroll
        for (int s = 0; s < 2; ++s)
#pragma unroll
          for (int r = 0; r < 4; ++r) zb[w][u][s][q * 4 + r][m] = acc[u][s][r];
    }
    __syncthreads();
    {
#pragma unroll
      for (int it = 0; it < 2; ++it) {
        int pid = tid + 256 * it;
        int gr = pid >> 2, c0 = (pid & 3) * 2;
        int mt = gr >> 4, rl = gr & 15, wv = mt >> 1, u = mt & 1;
        float hn[2];
#pragma unroll
        for (int d = 0; d < 2; ++d) {
          int c = c0 + d;
          float iv = zb[wv][u][0][rl][c]     + lb1[0][c];
          float fv = zb[wv][u][0][rl][c + 8] + lb1[1][c];
          float gv = zb[wv][u][1][rl][c]     + lb1[2][c];
          float ov = zb[wv][u][1][rl][c + 8] + lb1[3][c];
          float ig = sigf(iv), fg = sigf(fv), gg = tanhfast(gv), og = sigf(ov);
          float cn = fg * lc2[gr * 8 + c] + ig * gg;
          hn[d] = og * tanhfast(cn);
          lc2[gr * 8 + c] = cn;
        }
        stc2(h2w + (size_t)gr * H_ + 8 * j + c0, hn[0], hn[1]);
        if (t == T_ - 1) {
          lastp[(size_t)gr * H_ + 8 * j + c0]     = hn[0];
          lastp[(size_t)gr * H_ + 8 * j + c0 + 1] = hn[1];
        }
      }
    }
    gbar(arr, go, j, ++ph, 63);
  }
}

// ---------------------------------------------------------------------------
extern "C" void kernel_launch(void* const* d_in, const int* in_sizes, int n_in,
                              void* d_out, int out_size, void* d_ws, size_t ws_size,
                              hipStream_t stream) {
  const float* x    = (const float*)d_in[0];
  const float* k0   = (const float*)d_in[1];
  const float* r0   = (const float*)d_in[2];
  const float* b0   = (const float*)d_in[3];
  const float* k1   = (const float*)d_in[4];
  const float* r1   = (const float*)d_in[5];
  const float* b1   = (const float*)d_in[6];
  const float* W    = (const float*)d_in[7];
  const float* bias = (const float*)d_in[8];

  char* ws = (char*)d_ws;
  __hip_bfloat16* Wp1 = (__hip_bfloat16*)(ws + OFF_WP1);
  __hip_bfloat16* Wp2 = (__hip_bfloat16*)(ws + OFF_WP2);
  __hip_bfloat16* WpP = (__hip_bfloat16*)(ws + OFF_WPP);
  __hip_bfloat16* h1a = (__hip_bfloat16*)(ws + OFF_H1A);
  __hip_bfloat16* h1b = (__hip_bfloat16*)(ws + OFF_H1B);
  __hip_bfloat16* h2a = (__hip_bfloat16*)(ws + OFF_H2A);
  __hip_bfloat16* h2b = (__hip_bfloat16*)(ws + OFF_H2B);
  __hip_bfloat16* cur = (__hip_bfloat16*)(ws + OFF_CUR);
  unsigned*       bar = (unsigned*)(ws + OFF_BAR);

  pack_gi<<<576, 256, 0, stream>>>(k0, r0, 64, 18, Wp1);
  pack_gi<<<1024, 256, 0, stream>>>(k1, r1, 512, 32, Wp2);
  pack_plain<<<16, 256, 0, stream>>>(W, WpP);
  init_misc<<<256, 256, 0, stream>>>(h1a, h2a, bar);

  float* outp = (float*)d_out;
  float* last = outp + (size_t)B_ * (T_ - 1) * D_;

  rnn_persist<<<64, 256, 0, stream>>>(x, Wp1, Wp2, WpP, b0, b1, bias,
                                      cur, h1a, h1b, h2a, h2b, bar, outp, last);
}